// Round 4
// baseline (689.167 us; speedup 1.0000x reference)
//
#include <hip/hip_runtime.h>

// Problem constants (fixed by the reference setup)
#define B_ 64
#define T_ 1024
#define I_ 64
#define H_ 512
#define R_ 8
#define O_ 64

// fast tanh: tanh(x) = 1 - 2/(exp2(2*log2(e)*x)+1); well-behaved at +-inf
__device__ __forceinline__ float ftanh(float x) {
    float e = __builtin_amdgcn_exp2f(x * 2.8853900817779268f); // 2*log2(e)
    return 1.0f - 2.0f * __builtin_amdgcn_rcpf(e + 1.0f);
}

// DPP lane-permute move (VALU pipe, ~4cy; no LDS traffic)
template <int CTRL>
__device__ __forceinline__ float dppmov(float x) {
    return __int_as_float(__builtin_amdgcn_update_dpp(
        0, __float_as_int(x), CTRL, 0xF, 0xF, true));
}

// ---------------------------------------------------------------------------
// Kernel 1: drive[b,t,h] = 0.2*(sum_i u[b,t,i]*W_in[h,i] + b_in[h])
//                        + 0.05*noise[t,b,h]
// grid: (T/64, H/64, B), block 256. 64x64 tile: LDS 33.4KB -> 4 blocks/CU.
// ---------------------------------------------------------------------------
__global__ __launch_bounds__(256) void inp_gemm(
    const float* __restrict__ u, const float* __restrict__ W_in,
    const float* __restrict__ b_in, const float* __restrict__ noise,
    float* __restrict__ drive)
{
    __shared__ float4 su4[64 * 16];   // u tile [64 t][16 f4], no pad (broadcast)
    __shared__ float4 sw4[64 * 17];   // W tile [64 h][16 f4], row pad 17

    const int tid = threadIdx.x;
    const int t0 = blockIdx.x * 64;
    const int h0 = blockIdx.y * 64;
    const int b  = blockIdx.z;

    const float4* usrc = (const float4*)(u + (size_t)(b * T_ + t0) * I_);
    const float4* wsrc = (const float4*)(W_in + (size_t)h0 * I_);

    #pragma unroll
    for (int k = tid; k < 64 * 16; k += 256) {
        su4[k] = usrc[k];
        sw4[(k >> 4) * 17 + (k & 15)] = wsrc[k];
    }
    __syncthreads();

    const int tg = tid >> 4;   // 16 groups -> 4 t each
    const int hi = tid & 15;   // h = h0 + hi + 16*c

    float acc[4][4];
    #pragma unroll
    for (int a = 0; a < 4; ++a)
        #pragma unroll
        for (int c = 0; c < 4; ++c) acc[a][c] = 0.0f;

    #pragma unroll
    for (int i4 = 0; i4 < 16; ++i4) {
        float4 uv[4], wv[4];
        #pragma unroll
        for (int a = 0; a < 4; ++a) uv[a] = su4[(tg * 4 + a) * 16 + i4];
        #pragma unroll
        for (int c = 0; c < 4; ++c) wv[c] = sw4[(hi + 16 * c) * 17 + i4];
        #pragma unroll
        for (int a = 0; a < 4; ++a)
            #pragma unroll
            for (int c = 0; c < 4; ++c)
                acc[a][c] += uv[a].x * wv[c].x + uv[a].y * wv[c].y +
                             uv[a].z * wv[c].z + uv[a].w * wv[c].w;
    }

    #pragma unroll
    for (int c = 0; c < 4; ++c) {
        const int h = h0 + hi + 16 * c;
        float bi = b_in[h];
        #pragma unroll
        for (int a = 0; a < 4; ++a) {
            const int t = t0 + tg * 4 + a;
            float nz = noise[((size_t)t * B_ + b) * H_ + h];
            drive[(size_t)(b * T_ + t) * H_ + h] =
                0.2f * (acc[a][c] + bi) + 0.05f * nz;
        }
    }
}

// ---------------------------------------------------------------------------
// Kernel 2: chunk-parallel scan (contraction factor 0.8 -> W=48 warm-up,
// error ~0.8^48 = 2.3e-5). NC=16 -> 1024 blocks of 4 waves = 4 blocks/CU.
// ds_add_f32 cross-wave combine into 4 rotating 16-float slots; DPP fold
// butterfly; one raw lgkmcnt-only barrier per step; drive prefetch dist 3.
// ---------------------------------------------------------------------------
template <int NC>
__global__ __launch_bounds__(256) void scan_chunked(
    const float* __restrict__ x0,
    const float* __restrict__ Lm, const float* __restrict__ Mm,
    const float* __restrict__ Nm,
    const float* __restrict__ drive,
    float* __restrict__ traj, float* __restrict__ xlast)
{
    constexpr int C = T_ / NC;    // emitted steps per chunk
    constexpr int W = 48;         // warm-up steps (chunks c>=1); 0.8^48=2.3e-5

    const int tid  = threadIdx.x;
    const int ckid = blockIdx.x;
    const int b    = blockIdx.y;
    const int h0   = tid * 2;
    const int lane = tid & 63;
    const int lm   = lane & 15;
    // linear map g: g(1)=8, g(2)=4, g(4)=14, g(8)=1  (basis match for the
    // DPP stage masks 1,2,7,8 folding value-bits 8,4,2,1)
    const int gl = ((lm & 1) ? 8 : 0) ^ ((lm & 2) ? 4 : 0) ^
                   ((lm & 4) ? 14 : 0) ^ ((lm & 8) ? 1 : 0);

    // permuted projection weights: slot k holds value v = k ^ gl
    // (v<8 -> column v of M ; v>=8 -> column v-8 of N)
    float w0[16], w1[16];
    #pragma unroll
    for (int k = 0; k < 16; ++k) {
        const int v = k ^ gl;
        const float* src = (v < 8) ? Mm : Nm;
        const int col = v & 7;
        w0[k] = src[h0 * R_ + col];
        w1[k] = src[(h0 + 1) * R_ + col];
    }
    // L columns pre-scaled by tau*scale = 0.2/(H*H)
    float l0[8], l1[8];
    const float cs = 0.2f / (512.0f * 512.0f);
    #pragma unroll
    for (int j = 0; j < 8; ++j) {
        l0[j] = Lm[h0 * R_ + j] * cs;
        l1[j] = Lm[(h0 + 1) * R_ + j] * cs;
    }

    const int emit0 = ckid * C;
    const int warm  = (ckid == 0) ? 0 : W;
    const int t0s   = emit0 - warm;       // absolute first step
    const int tend  = emit0 + C;          // absolute end

    float2 xv;
    if (ckid == 0) xv = *(const float2*)(x0 + (size_t)b * H_ + h0);
    else           xv = make_float2(0.0f, 0.0f);

    const float2* dbase = (const float2*)drive + (size_t)b * (T_ * (H_ / 2)) + tid;
    float2*       tbase = (float2*)traj  + (size_t)b * (T_ * (H_ / 2)) + tid;

    // 4 rotating 16-float accumulation slots:
    //   slot s: ds_add at steps k==s (mod4), read at k==s+2, zeroed at k==s+3
    __shared__ __align__(16) float red[4][16];
    if (tid < 64) ((float*)red)[tid] = 0.0f;
    __syncthreads();

    // drive prefetch, distance 3, 4 rotating register slots
    float2 db[4];
    db[0] = dbase[(size_t)(t0s + 0) * 256];
    db[1] = dbase[(size_t)(t0s + 1) * 256];
    db[2] = dbase[(size_t)(t0s + 2) * 256];
    const float2* pf = dbase + (size_t)(t0s + 3) * 256;
    float2*       st = tbase + (size_t)emit0 * 256;
    float2 xstA, xstB;  // 2-deep store-source rotation (avoid WAR vm-waits)

#define STEP(T0, SA, XST, EMIT)                                             \
    do {                                                                    \
        const int t_ = (T0);                                                \
        constexpr int SR = ((SA) + 2) & 3;  /* combine slot (added k-2) */  \
        constexpr int SZ = ((SA) + 1) & 3;  /* zero slot (read at k-1) */   \
        constexpr int SP = ((SA) + 3) & 3;  /* prefetch slot (used k+3) */  \
        /* issue combine reads early: hidden under proj/folds */            \
        const float4* rp = (const float4*)(&red[SR][0]);                    \
        const float4 f0 = rp[0], f1 = rp[1], f2 = rp[2], f3 = rp[3];        \
        if (t_ + 3 < tend) db[SP] = *pf;                                    \
        pf += 256;                                                          \
        /* launch reduction of entering x (consumed 2 steps later) */       \
        const float r0 = ftanh(xv.x), r1 = ftanh(xv.y);                     \
        float p[16];                                                        \
        _Pragma("unroll")                                                   \
        for (int k = 0; k < 16; ++k) p[k] = r0 * w0[k] + r1 * w1[k];        \
        _Pragma("unroll")                                                   \
        for (int k = 0; k < 8; ++k) p[k] += dppmov<0xB1>(p[k + 8]);         \
        _Pragma("unroll")                                                   \
        for (int k = 0; k < 4; ++k) p[k] += dppmov<0x4E>(p[k + 4]);         \
        _Pragma("unroll")                                                   \
        for (int k = 0; k < 2; ++k) p[k] += dppmov<0x141>(p[k + 2]);        \
        float s_ = p[0] + dppmov<0x128>(p[1]);                              \
        s_ += __shfl_xor(s_, 16, 64);                                       \
        s_ += __shfl_xor(s_, 32, 64);                                       \
        if (lane < 16) {                                                    \
            red[SZ][lane] = 0.0f;           /* re-zero slot read at k-1 */  \
            atomicAdd(&red[SA][gl], s_);    /* ds_add_f32, no return */     \
        }                                                                   \
        /* combine (pure reads): prod & rec from slot SR */                 \
        float prod[8] = { f0.x * f2.x, f0.y * f2.y, f0.z * f2.z, f0.w * f2.w,\
                          f1.x * f3.x, f1.y * f3.y, f1.z * f3.z, f1.w * f3.w };\
        float rec0 = 0.0f, rec1 = 0.0f;                                     \
        _Pragma("unroll")                                                   \
        for (int j = 0; j < 8; ++j) { rec0 += l0[j] * prod[j];              \
                                      rec1 += l1[j] * prod[j]; }            \
        /* state update */                                                  \
        const float2 dv = db[SA];                                           \
        xv.x = fmaf(0.8f, xv.x, dv.x + rec0);                               \
        xv.y = fmaf(0.8f, xv.y, dv.y + rec1);                               \
        if (EMIT) { XST = xv; *st = XST; st += 256; }                       \
        /* end-of-step barrier: order LDS only; vmem stays in flight */     \
        asm volatile("s_waitcnt lgkmcnt(0)\n\ts_barrier" ::: "memory");     \
    } while (0)

    // warm-up (no store); warm is 0 or 48, both multiples of 4
    for (int k = 0; k < warm; k += 4) {
        STEP(t0s + k + 0, 0, xstA, false);
        STEP(t0s + k + 1, 1, xstB, false);
        STEP(t0s + k + 2, 2, xstA, false);
        STEP(t0s + k + 3, 3, xstB, false);
    }
    // emit
    for (int k = warm; k < warm + C; k += 4) {
        STEP(t0s + k + 0, 0, xstA, true);
        STEP(t0s + k + 1, 1, xstB, true);
        STEP(t0s + k + 2, 2, xstA, true);
        STEP(t0s + k + 3, 3, xstB, true);
    }
#undef STEP

    if (tend == T_)
        *(float2*)(xlast + (size_t)b * H_ + h0) = xv;
}

// ---------------------------------------------------------------------------
// Kernel 3 v2: output[b,t,o] = sum_h tanh(traj[b,t,h])*W_out[o,h] + b_out[o]
// grid: (T/128, B) = 512 blocks, 256 threads. Tile 128t x 64o, thread 8t x 4o
// (12 LDS reads per 128 FMA = 1.5 B/FLOP, was 2.0). K=512 in 8 chunks of 64
// with REGISTER-PREFETCH double buffering: next chunk's global loads issue
// right after the post-write barrier and land during compute, so the
// vmcnt-drain at the next barrier costs ~nothing. tanh fused in reg->LDS.
// ---------------------------------------------------------------------------
__global__ __launch_bounds__(256) void out_gemm(
    const float* __restrict__ traj, const float* __restrict__ W_out,
    const float* __restrict__ b_out, float* __restrict__ out)
{
    __shared__ float4 sa4[128 * 17];  // tanh(traj) tile [128 t][16 f4]
    __shared__ float4 sb4[64 * 17];   // W_out tile [64 o][16 f4]

    const int tid = threadIdx.x;
    const int t0 = blockIdx.x * 128;
    const int b  = blockIdx.y;
    const int tg = tid >> 4;   // 16 groups -> 8 t each
    const int oi = tid & 15;   // o = oi + 16*c

    const float4* tsrc = (const float4*)(traj + (size_t)(b * T_ + t0) * H_);
    const float4* wsrc = (const float4*)W_out;

    float acc[8][4];
    #pragma unroll
    for (int a = 0; a < 8; ++a)
        #pragma unroll
        for (int c = 0; c < 4; ++c) acc[a][c] = 0.0f;

    float4 pa[8], pb[4];

#define LOADC(HC)                                                            \
    do {                                                                     \
        _Pragma("unroll")                                                    \
        for (int j = 0; j < 8; ++j) {                                        \
            int k = tid + 256 * j;                                           \
            pa[j] = tsrc[(size_t)(k >> 4) * 128 + (HC) * 16 + (k & 15)];     \
        }                                                                    \
        _Pragma("unroll")                                                    \
        for (int j = 0; j < 4; ++j) {                                        \
            int k = tid + 256 * j;                                           \
            pb[j] = wsrc[(size_t)(k >> 4) * 128 + (HC) * 16 + (k & 15)];     \
        }                                                                    \
    } while (0)

    LOADC(0);

    for (int hc = 0; hc < 8; ++hc) {
        __syncthreads();   // prior compute done with LDS; prefetch regs landed
        #pragma unroll
        for (int j = 0; j < 8; ++j) {
            int k = tid + 256 * j;
            float4 v = pa[j];
            v.x = ftanh(v.x); v.y = ftanh(v.y); v.z = ftanh(v.z); v.w = ftanh(v.w);
            sa4[(k >> 4) * 17 + (k & 15)] = v;
        }
        #pragma unroll
        for (int j = 0; j < 4; ++j) {
            int k = tid + 256 * j;
            sb4[(k >> 4) * 17 + (k & 15)] = pb[j];
        }
        __syncthreads();
        if (hc < 7) LOADC(hc + 1);   // in flight during compute below

        #pragma unroll
        for (int i4 = 0; i4 < 16; ++i4) {
            float4 av[8], bv[4];
            #pragma unroll
            for (int a = 0; a < 8; ++a) av[a] = sa4[(tg * 8 + a) * 17 + i4];
            #pragma unroll
            for (int c = 0; c < 4; ++c) bv[c] = sb4[(oi + 16 * c) * 17 + i4];
            #pragma unroll
            for (int a = 0; a < 8; ++a)
                #pragma unroll
                for (int c = 0; c < 4; ++c)
                    acc[a][c] += av[a].x * bv[c].x + av[a].y * bv[c].y +
                                 av[a].z * bv[c].z + av[a].w * bv[c].w;
        }
    }
#undef LOADC

    #pragma unroll
    for (int c = 0; c < 4; ++c) {
        float bo = b_out[oi + 16 * c];
        #pragma unroll
        for (int a = 0; a < 8; ++a)
            out[(size_t)(b * T_ + t0 + tg * 8 + a) * O_ + oi + 16 * c] =
                acc[a][c] + bo;
    }
}

// ---------------------------------------------------------------------------
extern "C" void kernel_launch(void* const* d_in, const int* in_sizes, int n_in,
                              void* d_out, int out_size, void* d_ws, size_t ws_size,
                              hipStream_t stream)
{
    const float* u     = (const float*)d_in[0];
    const float* x0    = (const float*)d_in[1];
    const float* noise = (const float*)d_in[2];
    const float* L     = (const float*)d_in[3];
    const float* M     = (const float*)d_in[4];
    const float* N     = (const float*)d_in[5];
    const float* W_in  = (const float*)d_in[6];
    const float* b_in  = (const float*)d_in[7];
    const float* W_out = (const float*)d_in[8];
    const float* b_out = (const float*)d_in[9];

    float* out   = (float*)d_out;                       // [B,T,O]
    float* xlast = out + (size_t)B_ * T_ * O_;          // [B,H]
    float* traj  = xlast + (size_t)B_ * H_;             // [B,T,H]

    const size_t drive_bytes = (size_t)B_ * T_ * H_ * sizeof(float);

    if (ws_size >= drive_bytes) {
        // chunk-parallel path: drive lives in the workspace
        float* drive = (float*)d_ws;
        inp_gemm<<<dim3(T_ / 64, H_ / 64, B_), 256, 0, stream>>>(
            u, W_in, b_in, noise, drive);
        scan_chunked<16><<<dim3(16, B_), 256, 0, stream>>>(
            x0, L, M, N, drive, traj, xlast);
    } else {
        // fallback: exact serial in-place scan (drive aliases traj)
        inp_gemm<<<dim3(T_ / 64, H_ / 64, B_), 256, 0, stream>>>(
            u, W_in, b_in, noise, traj);
        scan_chunked<1><<<dim3(1, B_), 256, 0, stream>>>(
            x0, L, M, N, traj, traj, xlast);
    }

    out_gemm<<<dim3(T_ / 128, B_), 256, 0, stream>>>(traj, W_out, b_out, out);
}

// Round 5
// 559.980 us; speedup vs baseline: 1.2307x; 1.2307x over previous
//
#include <hip/hip_runtime.h>

// Problem constants (fixed by the reference setup)
#define B_ 64
#define T_ 1024
#define I_ 64
#define H_ 512
#define R_ 8
#define O_ 64

// fast tanh: tanh(x) = 1 - 2/(exp2(2*log2(e)*x)+1); well-behaved at +-inf
__device__ __forceinline__ float ftanh(float x) {
    float e = __builtin_amdgcn_exp2f(x * 2.8853900817779268f); // 2*log2(e)
    return 1.0f - 2.0f * __builtin_amdgcn_rcpf(e + 1.0f);
}

// DPP lane-permute move (VALU pipe, ~4cy; no LDS traffic)
template <int CTRL>
__device__ __forceinline__ float dppmov(float x) {
    return __int_as_float(__builtin_amdgcn_update_dpp(
        0, __float_as_int(x), CTRL, 0xF, 0xF, true));
}

// ---------------------------------------------------------------------------
// Kernel 1: drive[b,t,h] = 0.2*(sum_i u[b,t,i]*W_in[h,i] + b_in[h])
//                        + 0.05*noise[t,b,h]
// grid: (T/64, H/64, B), block 256. 64x64 tile: LDS 33.4KB.
// ---------------------------------------------------------------------------
__global__ __launch_bounds__(256) void inp_gemm(
    const float* __restrict__ u, const float* __restrict__ W_in,
    const float* __restrict__ b_in, const float* __restrict__ noise,
    float* __restrict__ drive)
{
    __shared__ float4 su4[64 * 16];   // u tile [64 t][16 f4], no pad (broadcast)
    __shared__ float4 sw4[64 * 17];   // W tile [64 h][16 f4], row pad 17

    const int tid = threadIdx.x;
    const int t0 = blockIdx.x * 64;
    const int h0 = blockIdx.y * 64;
    const int b  = blockIdx.z;

    const float4* usrc = (const float4*)(u + (size_t)(b * T_ + t0) * I_);
    const float4* wsrc = (const float4*)(W_in + (size_t)h0 * I_);

    #pragma unroll
    for (int k = tid; k < 64 * 16; k += 256) {
        su4[k] = usrc[k];
        sw4[(k >> 4) * 17 + (k & 15)] = wsrc[k];
    }
    __syncthreads();

    const int tg = tid >> 4;   // 16 groups -> 4 t each
    const int hi = tid & 15;   // h = h0 + hi + 16*c

    float acc[4][4];
    #pragma unroll
    for (int a = 0; a < 4; ++a)
        #pragma unroll
        for (int c = 0; c < 4; ++c) acc[a][c] = 0.0f;

    #pragma unroll
    for (int i4 = 0; i4 < 16; ++i4) {
        float4 uv[4], wv[4];
        #pragma unroll
        for (int a = 0; a < 4; ++a) uv[a] = su4[(tg * 4 + a) * 16 + i4];
        #pragma unroll
        for (int c = 0; c < 4; ++c) wv[c] = sw4[(hi + 16 * c) * 17 + i4];
        #pragma unroll
        for (int a = 0; a < 4; ++a)
            #pragma unroll
            for (int c = 0; c < 4; ++c)
                acc[a][c] += uv[a].x * wv[c].x + uv[a].y * wv[c].y +
                             uv[a].z * wv[c].z + uv[a].w * wv[c].w;
    }

    #pragma unroll
    for (int c = 0; c < 4; ++c) {
        const int h = h0 + hi + 16 * c;
        float bi = b_in[h];
        #pragma unroll
        for (int a = 0; a < 4; ++a) {
            const int t = t0 + tg * 4 + a;
            float nz = noise[((size_t)t * B_ + b) * H_ + h];
            drive[(size_t)(b * T_ + t) * H_ + h] =
                0.2f * (acc[a][c] + bi) + 0.05f * nz;
        }
    }
}

// ---------------------------------------------------------------------------
// Kernel 2: chunk-parallel scan (contraction 0.8 -> W=48 warm-up, err 2.3e-5).
// NC=16 -> 1024 blocks x 4 waves.
//
// v4: barrier every TWO steps. 8 rotating 16-float slots: slot s gets
// ds_adds at step k==s (mod 8), is read at k+2, re-zeroed at k+4. All
// cross-thread {add->read, read->zero, zero->add} pairs are 2 steps apart
// = separated by >=1 barrier (barriers after odd steps). Within a
// 2-step window the six touched slot-roles are pairwise distinct.
// ---------------------------------------------------------------------------
template <int NC>
__global__ __launch_bounds__(256) void scan_chunked(
    const float* __restrict__ x0,
    const float* __restrict__ Lm, const float* __restrict__ Mm,
    const float* __restrict__ Nm,
    const float* __restrict__ drive,
    float* __restrict__ traj, float* __restrict__ xlast)
{
    constexpr int C = T_ / NC;    // emitted steps per chunk (mult of 8)
    constexpr int W = 48;         // warm-up steps (chunks c>=1); 0.8^48=2.3e-5

    const int tid  = threadIdx.x;
    const int ckid = blockIdx.x;
    const int b    = blockIdx.y;
    const int h0   = tid * 2;
    const int lane = tid & 63;
    const int lm   = lane & 15;
    // linear map g: g(1)=8, g(2)=4, g(4)=14, g(8)=1  (basis match for the
    // DPP stage masks 1,2,7,8 folding value-bits 8,4,2,1)
    const int gl = ((lm & 1) ? 8 : 0) ^ ((lm & 2) ? 4 : 0) ^
                   ((lm & 4) ? 14 : 0) ^ ((lm & 8) ? 1 : 0);

    // permuted projection weights: slot k holds value v = k ^ gl
    float w0[16], w1[16];
    #pragma unroll
    for (int k = 0; k < 16; ++k) {
        const int v = k ^ gl;
        const float* src = (v < 8) ? Mm : Nm;
        const int col = v & 7;
        w0[k] = src[h0 * R_ + col];
        w1[k] = src[(h0 + 1) * R_ + col];
    }
    // L columns pre-scaled by tau*scale = 0.2/(H*H)
    float l0[8], l1[8];
    const float cs = 0.2f / (512.0f * 512.0f);
    #pragma unroll
    for (int j = 0; j < 8; ++j) {
        l0[j] = Lm[h0 * R_ + j] * cs;
        l1[j] = Lm[(h0 + 1) * R_ + j] * cs;
    }

    const int emit0 = ckid * C;
    const int warm  = (ckid == 0) ? 0 : W;
    const int t0s   = emit0 - warm;       // absolute first step
    const int tend  = emit0 + C;          // absolute end

    float2 xv;
    if (ckid == 0) xv = *(const float2*)(x0 + (size_t)b * H_ + h0);
    else           xv = make_float2(0.0f, 0.0f);

    const float2* dbase = (const float2*)drive + (size_t)b * (T_ * (H_ / 2)) + tid;
    float2*       tbase = (float2*)traj  + (size_t)b * (T_ * (H_ / 2)) + tid;

    // 8 rotating 16-float accumulation slots (see header comment)
    __shared__ __align__(16) float red[8][16];
    if (tid < 128) ((float*)red)[tid] = 0.0f;
    __syncthreads();

    // drive prefetch, distance 3, 4 rotating register slots
    float2 db[4];
    db[0] = dbase[(size_t)(t0s + 0) * 256];
    db[1] = dbase[(size_t)(t0s + 1) * 256];
    db[2] = dbase[(size_t)(t0s + 2) * 256];
    const float2* pf = dbase + (size_t)(t0s + 3) * 256;
    float2*       st = tbase + (size_t)emit0 * 256;
    float2 xstA, xstB;  // 2-deep store-source rotation (avoid WAR vm-waits)

#define STEP(T0, SA, XST, EMIT)                                             \
    do {                                                                    \
        const int t_ = (T0);                                                \
        constexpr int SR = ((SA) + 6) & 7;  /* read slot (added k-2) */     \
        constexpr int SZ = ((SA) + 4) & 7;  /* zero slot (read at k-2) */   \
        constexpr int DP = ((SA) + 3) & 3;  /* prefetch slot (used k+3) */  \
        constexpr int DA = (SA) & 3;        /* drive slot consumed now */   \
        /* issue combine reads early: hidden under proj/folds */            \
        const float4* rp = (const float4*)(&red[SR][0]);                    \
        const float4 f0 = rp[0], f1 = rp[1], f2 = rp[2], f3 = rp[3];        \
        if (t_ + 3 < tend) db[DP] = *pf;                                    \
        pf += 256;                                                          \
        /* launch reduction of entering x (consumed 2 steps later) */       \
        const float r0 = ftanh(xv.x), r1 = ftanh(xv.y);                     \
        float p[16];                                                        \
        _Pragma("unroll")                                                   \
        for (int k = 0; k < 16; ++k) p[k] = r0 * w0[k] + r1 * w1[k];        \
        _Pragma("unroll")                                                   \
        for (int k = 0; k < 8; ++k) p[k] += dppmov<0xB1>(p[k + 8]);         \
        _Pragma("unroll")                                                   \
        for (int k = 0; k < 4; ++k) p[k] += dppmov<0x4E>(p[k + 4]);         \
        _Pragma("unroll")                                                   \
        for (int k = 0; k < 2; ++k) p[k] += dppmov<0x141>(p[k + 2]);        \
        float s_ = p[0] + dppmov<0x128>(p[1]);                              \
        s_ += __shfl_xor(s_, 16, 64);                                       \
        s_ += __shfl_xor(s_, 32, 64);                                       \
        if (lane < 16) {                                                    \
            red[SZ][lane] = 0.0f;           /* re-zero (read 2 steps ago) */\
            atomicAdd(&red[SA & 7][gl], s_);/* ds_add_f32, no return */     \
        }                                                                   \
        /* combine (pure reads): prod & rec from slot SR */                 \
        float prod[8] = { f0.x * f2.x, f0.y * f2.y, f0.z * f2.z, f0.w * f2.w,\
                          f1.x * f3.x, f1.y * f3.y, f1.z * f3.z, f1.w * f3.w };\
        float rec0 = 0.0f, rec1 = 0.0f;                                     \
        _Pragma("unroll")                                                   \
        for (int j = 0; j < 8; ++j) { rec0 += l0[j] * prod[j];              \
                                      rec1 += l1[j] * prod[j]; }            \
        /* state update */                                                  \
        const float2 dv = db[DA];                                           \
        xv.x = fmaf(0.8f, xv.x, dv.x + rec0);                               \
        xv.y = fmaf(0.8f, xv.y, dv.y + rec1);                               \
        if (EMIT) { XST = xv; *st = XST; st += 256; }                       \
        /* barrier every 2nd step: order LDS only; vmem stays in flight */  \
        if ((SA) & 1)                                                       \
            asm volatile("s_waitcnt lgkmcnt(0)\n\ts_barrier" ::: "memory"); \
    } while (0)

    // warm-up (no store); warm is 0 or 48, both multiples of 8
    for (int k = 0; k < warm; k += 8) {
        STEP(t0s + k + 0, 0, xstA, false);
        STEP(t0s + k + 1, 1, xstB, false);
        STEP(t0s + k + 2, 2, xstA, false);
        STEP(t0s + k + 3, 3, xstB, false);
        STEP(t0s + k + 4, 4, xstA, false);
        STEP(t0s + k + 5, 5, xstB, false);
        STEP(t0s + k + 6, 6, xstA, false);
        STEP(t0s + k + 7, 7, xstB, false);
    }
    // emit (C multiple of 8)
    for (int k = warm; k < warm + C; k += 8) {
        STEP(t0s + k + 0, 0, xstA, true);
        STEP(t0s + k + 1, 1, xstB, true);
        STEP(t0s + k + 2, 2, xstA, true);
        STEP(t0s + k + 3, 3, xstB, true);
        STEP(t0s + k + 4, 4, xstA, true);
        STEP(t0s + k + 5, 5, xstB, true);
        STEP(t0s + k + 6, 6, xstA, true);
        STEP(t0s + k + 7, 7, xstB, true);
    }
#undef STEP

    if (tend == T_)
        *(float2*)(xlast + (size_t)b * H_ + h0) = xv;
}

// ---------------------------------------------------------------------------
// Kernel 3 v3: output[b,t,o] = sum_h tanh(traj[b,t,h])*W_out[o,h] + b_out[o]
// grid: (T/64, B) = 1024 blocks, 256 threads, 64t x 64o tile, thread 4t x 4o.
// Cross-chunk register prefetch sized to pa[4]+pb[4] = 32 VGPR only (the R4
// 128t variant spilled at 256 VGPR -> 282MB scratch writes). Loads for chunk
// hc+1 issue right after the writes-visible barrier and land during compute.
// ---------------------------------------------------------------------------
__global__ __launch_bounds__(256) void out_gemm(
    const float* __restrict__ traj, const float* __restrict__ W_out,
    const float* __restrict__ b_out, float* __restrict__ out)
{
    __shared__ float4 sa4[64 * 17];  // tanh(traj) tile [64 t][16 f4]
    __shared__ float4 sb4[64 * 17];  // W_out tile [64 o][16 f4]

    const int tid = threadIdx.x;
    const int t0 = blockIdx.x * 64;
    const int b  = blockIdx.y;
    const int tg = tid >> 4, oi = tid & 15;

    const float4* tsrc = (const float4*)(traj + (size_t)(b * T_ + t0) * H_);
    const float4* wsrc = (const float4*)W_out;

    float acc[4][4];
    #pragma unroll
    for (int a = 0; a < 4; ++a)
        #pragma unroll
        for (int c = 0; c < 4; ++c) acc[a][c] = 0.0f;

    float4 pa[4], pb[4];

#define LOADC(HC)                                                            \
    do {                                                                     \
        _Pragma("unroll")                                                    \
        for (int j = 0; j < 4; ++j) {                                        \
            int k = tid + 256 * j;                                           \
            pa[j] = tsrc[(size_t)(k >> 4) * 128 + (HC) * 16 + (k & 15)];     \
            pb[j] = wsrc[(size_t)(k >> 4) * 128 + (HC) * 16 + (k & 15)];     \
        }                                                                    \
    } while (0)

    LOADC(0);

    for (int hc = 0; hc < 8; ++hc) {
        if (hc > 0) __syncthreads();   // prior compute done reading LDS
        #pragma unroll
        for (int j = 0; j < 4; ++j) {
            int k = tid + 256 * j;
            float4 v = pa[j];
            v.x = ftanh(v.x); v.y = ftanh(v.y); v.z = ftanh(v.z); v.w = ftanh(v.w);
            sa4[(k >> 4) * 17 + (k & 15)] = v;
            sb4[(k >> 4) * 17 + (k & 15)] = pb[j];
        }
        __syncthreads();               // writes visible
        if (hc < 7) LOADC(hc + 1);     // in flight during compute below

        #pragma unroll
        for (int i4 = 0; i4 < 16; ++i4) {
            float4 av[4], bv[4];
            #pragma unroll
            for (int a = 0; a < 4; ++a) av[a] = sa4[(tg * 4 + a) * 17 + i4];
            #pragma unroll
            for (int c = 0; c < 4; ++c) bv[c] = sb4[(oi + 16 * c) * 17 + i4];
            #pragma unroll
            for (int a = 0; a < 4; ++a)
                #pragma unroll
                for (int c = 0; c < 4; ++c)
                    acc[a][c] += av[a].x * bv[c].x + av[a].y * bv[c].y +
                                 av[a].z * bv[c].z + av[a].w * bv[c].w;
        }
    }
#undef LOADC

    #pragma unroll
    for (int c = 0; c < 4; ++c) {
        float bo = b_out[oi + 16 * c];
        #pragma unroll
        for (int a = 0; a < 4; ++a)
            out[(size_t)(b * T_ + t0 + tg * 4 + a) * O_ + oi + 16 * c] =
                acc[a][c] + bo;
    }
}

// ---------------------------------------------------------------------------
extern "C" void kernel_launch(void* const* d_in, const int* in_sizes, int n_in,
                              void* d_out, int out_size, void* d_ws, size_t ws_size,
                              hipStream_t stream)
{
    const float* u     = (const float*)d_in[0];
    const float* x0    = (const float*)d_in[1];
    const float* noise = (const float*)d_in[2];
    const float* L     = (const float*)d_in[3];
    const float* M     = (const float*)d_in[4];
    const float* N     = (const float*)d_in[5];
    const float* W_in  = (const float*)d_in[6];
    const float* b_in  = (const float*)d_in[7];
    const float* W_out = (const float*)d_in[8];
    const float* b_out = (const float*)d_in[9];

    float* out   = (float*)d_out;                       // [B,T,O]
    float* xlast = out + (size_t)B_ * T_ * O_;          // [B,H]
    float* traj  = xlast + (size_t)B_ * H_;             // [B,T,H]

    const size_t drive_bytes = (size_t)B_ * T_ * H_ * sizeof(float);

    if (ws_size >= drive_bytes) {
        // chunk-parallel path: drive lives in the workspace
        float* drive = (float*)d_ws;
        inp_gemm<<<dim3(T_ / 64, H_ / 64, B_), 256, 0, stream>>>(
            u, W_in, b_in, noise, drive);
        scan_chunked<16><<<dim3(16, B_), 256, 0, stream>>>(
            x0, L, M, N, drive, traj, xlast);
    } else {
        // fallback: exact serial in-place scan (drive aliases traj)
        inp_gemm<<<dim3(T_ / 64, H_ / 64, B_), 256, 0, stream>>>(
            u, W_in, b_in, noise, traj);
        scan_chunked<1><<<dim3(1, B_), 256, 0, stream>>>(
            x0, L, M, N, traj, traj, xlast);
    }

    out_gemm<<<dim3(T_ / 64, B_), 256, 0, stream>>>(traj, W_out, b_out, out);
}

// Round 6
// 470.768 us; speedup vs baseline: 1.4639x; 1.1895x over previous
//
#include <hip/hip_runtime.h>

// Problem constants (fixed by the reference setup)
#define B_ 64
#define T_ 1024
#define I_ 64
#define H_ 512
#define R_ 8
#define O_ 64

typedef __attribute__((ext_vector_type(8))) short bf16x8;
typedef __attribute__((ext_vector_type(4))) float f32x4;

// fast tanh: tanh(x) = 1 - 2/(exp2(2*log2(e)*x)+1); well-behaved at +-inf
__device__ __forceinline__ float ftanh(float x) {
    float e = __builtin_amdgcn_exp2f(x * 2.8853900817779268f); // 2*log2(e)
    return 1.0f - 2.0f * __builtin_amdgcn_rcpf(e + 1.0f);
}

// round-to-nearest-even bf16, returned as low 16 bits
__device__ __forceinline__ unsigned int bfr(float a) {
    unsigned int u = __float_as_uint(a);
    return (u + 0x7FFFu + ((u >> 16) & 1u)) >> 16;
}

// DPP lane-permute move (VALU pipe, ~4cy; no LDS traffic)
template <int CTRL>
__device__ __forceinline__ float dppmov(float x) {
    return __int_as_float(__builtin_amdgcn_update_dpp(
        0, __float_as_int(x), CTRL, 0xF, 0xF, true));
}

// ---------------------------------------------------------------------------
// Kernel 1: drive[b,t,h] = 0.2*(sum_i u[b,t,i]*W_in[h,i] + b_in[h])
//                        + 0.05*noise[t,b,h]
// grid: (T/64, H/64, B), block 256. 64x64 tile: LDS 33.4KB.
// ---------------------------------------------------------------------------
__global__ __launch_bounds__(256) void inp_gemm(
    const float* __restrict__ u, const float* __restrict__ W_in,
    const float* __restrict__ b_in, const float* __restrict__ noise,
    float* __restrict__ drive)
{
    __shared__ float4 su4[64 * 16];   // u tile [64 t][16 f4], no pad (broadcast)
    __shared__ float4 sw4[64 * 17];   // W tile [64 h][16 f4], row pad 17

    const int tid = threadIdx.x;
    const int t0 = blockIdx.x * 64;
    const int h0 = blockIdx.y * 64;
    const int b  = blockIdx.z;

    const float4* usrc = (const float4*)(u + (size_t)(b * T_ + t0) * I_);
    const float4* wsrc = (const float4*)(W_in + (size_t)h0 * I_);

    #pragma unroll
    for (int k = tid; k < 64 * 16; k += 256) {
        su4[k] = usrc[k];
        sw4[(k >> 4) * 17 + (k & 15)] = wsrc[k];
    }
    __syncthreads();

    const int tg = tid >> 4;   // 16 groups -> 4 t each
    const int hi = tid & 15;   // h = h0 + hi + 16*c

    float acc[4][4];
    #pragma unroll
    for (int a = 0; a < 4; ++a)
        #pragma unroll
        for (int c = 0; c < 4; ++c) acc[a][c] = 0.0f;

    #pragma unroll
    for (int i4 = 0; i4 < 16; ++i4) {
        float4 uv[4], wv[4];
        #pragma unroll
        for (int a = 0; a < 4; ++a) uv[a] = su4[(tg * 4 + a) * 16 + i4];
        #pragma unroll
        for (int c = 0; c < 4; ++c) wv[c] = sw4[(hi + 16 * c) * 17 + i4];
        #pragma unroll
        for (int a = 0; a < 4; ++a)
            #pragma unroll
            for (int c = 0; c < 4; ++c)
                acc[a][c] += uv[a].x * wv[c].x + uv[a].y * wv[c].y +
                             uv[a].z * wv[c].z + uv[a].w * wv[c].w;
    }

    #pragma unroll
    for (int c = 0; c < 4; ++c) {
        const int h = h0 + hi + 16 * c;
        float bi = b_in[h];
        #pragma unroll
        for (int a = 0; a < 4; ++a) {
            const int t = t0 + tg * 4 + a;
            float nz = noise[((size_t)t * B_ + b) * H_ + h];
            drive[(size_t)(b * T_ + t) * H_ + h] =
                0.2f * (acc[a][c] + bi) + 0.05f * nz;
        }
    }
}

// ---------------------------------------------------------------------------
// Kernel 2: chunk-parallel scan (contraction 0.8 -> W=48 warm-up, err 2.3e-5).
// NC=16 -> 1024 blocks x 4 waves. Barrier every 2 steps, 8 rotating
// ds_add_f32 slots, DPP fold-butterfly, drive prefetch distance 3.
// (unchanged from R5)
// ---------------------------------------------------------------------------
template <int NC>
__global__ __launch_bounds__(256) void scan_chunked(
    const float* __restrict__ x0,
    const float* __restrict__ Lm, const float* __restrict__ Mm,
    const float* __restrict__ Nm,
    const float* __restrict__ drive,
    float* __restrict__ traj, float* __restrict__ xlast)
{
    constexpr int C = T_ / NC;    // emitted steps per chunk (mult of 8)
    constexpr int W = 48;         // warm-up steps (chunks c>=1); 0.8^48=2.3e-5

    const int tid  = threadIdx.x;
    const int ckid = blockIdx.x;
    const int b    = blockIdx.y;
    const int h0   = tid * 2;
    const int lane = tid & 63;
    const int lm   = lane & 15;
    // linear map g: g(1)=8, g(2)=4, g(4)=14, g(8)=1  (basis match for the
    // DPP stage masks 1,2,7,8 folding value-bits 8,4,2,1)
    const int gl = ((lm & 1) ? 8 : 0) ^ ((lm & 2) ? 4 : 0) ^
                   ((lm & 4) ? 14 : 0) ^ ((lm & 8) ? 1 : 0);

    // permuted projection weights: slot k holds value v = k ^ gl
    float w0[16], w1[16];
    #pragma unroll
    for (int k = 0; k < 16; ++k) {
        const int v = k ^ gl;
        const float* src = (v < 8) ? Mm : Nm;
        const int col = v & 7;
        w0[k] = src[h0 * R_ + col];
        w1[k] = src[(h0 + 1) * R_ + col];
    }
    // L columns pre-scaled by tau*scale = 0.2/(H*H)
    float l0[8], l1[8];
    const float cs = 0.2f / (512.0f * 512.0f);
    #pragma unroll
    for (int j = 0; j < 8; ++j) {
        l0[j] = Lm[h0 * R_ + j] * cs;
        l1[j] = Lm[(h0 + 1) * R_ + j] * cs;
    }

    const int emit0 = ckid * C;
    const int warm  = (ckid == 0) ? 0 : W;
    const int t0s   = emit0 - warm;       // absolute first step
    const int tend  = emit0 + C;          // absolute end

    float2 xv;
    if (ckid == 0) xv = *(const float2*)(x0 + (size_t)b * H_ + h0);
    else           xv = make_float2(0.0f, 0.0f);

    const float2* dbase = (const float2*)drive + (size_t)b * (T_ * (H_ / 2)) + tid;
    float2*       tbase = (float2*)traj  + (size_t)b * (T_ * (H_ / 2)) + tid;

    // 8 rotating 16-float accumulation slots
    __shared__ __align__(16) float red[8][16];
    if (tid < 128) ((float*)red)[tid] = 0.0f;
    __syncthreads();

    // drive prefetch, distance 3, 4 rotating register slots
    float2 db[4];
    db[0] = dbase[(size_t)(t0s + 0) * 256];
    db[1] = dbase[(size_t)(t0s + 1) * 256];
    db[2] = dbase[(size_t)(t0s + 2) * 256];
    const float2* pf = dbase + (size_t)(t0s + 3) * 256;
    float2*       st = tbase + (size_t)emit0 * 256;
    float2 xstA, xstB;  // 2-deep store-source rotation (avoid WAR vm-waits)

#define STEP(T0, SA, XST, EMIT)                                             \
    do {                                                                    \
        const int t_ = (T0);                                                \
        constexpr int SR = ((SA) + 6) & 7;  /* read slot (added k-2) */     \
        constexpr int SZ = ((SA) + 4) & 7;  /* zero slot (read at k-2) */   \
        constexpr int DP = ((SA) + 3) & 3;  /* prefetch slot (used k+3) */  \
        constexpr int DA = (SA) & 3;        /* drive slot consumed now */   \
        /* issue combine reads early: hidden under proj/folds */            \
        const float4* rp = (const float4*)(&red[SR][0]);                    \
        const float4 f0 = rp[0], f1 = rp[1], f2 = rp[2], f3 = rp[3];        \
        if (t_ + 3 < tend) db[DP] = *pf;                                    \
        pf += 256;                                                          \
        /* launch reduction of entering x (consumed 2 steps later) */       \
        const float r0 = ftanh(xv.x), r1 = ftanh(xv.y);                     \
        float p[16];                                                        \
        _Pragma("unroll")                                                   \
        for (int k = 0; k < 16; ++k) p[k] = r0 * w0[k] + r1 * w1[k];        \
        _Pragma("unroll")                                                   \
        for (int k = 0; k < 8; ++k) p[k] += dppmov<0xB1>(p[k + 8]);         \
        _Pragma("unroll")                                                   \
        for (int k = 0; k < 4; ++k) p[k] += dppmov<0x4E>(p[k + 4]);         \
        _Pragma("unroll")                                                   \
        for (int k = 0; k < 2; ++k) p[k] += dppmov<0x141>(p[k + 2]);        \
        float s_ = p[0] + dppmov<0x128>(p[1]);                              \
        s_ += __shfl_xor(s_, 16, 64);                                       \
        s_ += __shfl_xor(s_, 32, 64);                                       \
        if (lane < 16) {                                                    \
            red[SZ][lane] = 0.0f;           /* re-zero (read 2 steps ago) */\
            atomicAdd(&red[SA & 7][gl], s_);/* ds_add_f32, no return */     \
        }                                                                   \
        /* combine (pure reads): prod & rec from slot SR */                 \
        float prod[8] = { f0.x * f2.x, f0.y * f2.y, f0.z * f2.z, f0.w * f2.w,\
                          f1.x * f3.x, f1.y * f3.y, f1.z * f3.z, f1.w * f3.w };\
        float rec0 = 0.0f, rec1 = 0.0f;                                     \
        _Pragma("unroll")                                                   \
        for (int j = 0; j < 8; ++j) { rec0 += l0[j] * prod[j];              \
                                      rec1 += l1[j] * prod[j]; }            \
        /* state update */                                                  \
        const float2 dv = db[DA];                                           \
        xv.x = fmaf(0.8f, xv.x, dv.x + rec0);                               \
        xv.y = fmaf(0.8f, xv.y, dv.y + rec1);                               \
        if (EMIT) { XST = xv; *st = XST; st += 256; }                       \
        /* barrier every 2nd step: order LDS only; vmem stays in flight */  \
        if ((SA) & 1)                                                       \
            asm volatile("s_waitcnt lgkmcnt(0)\n\ts_barrier" ::: "memory"); \
    } while (0)

    // warm-up (no store); warm is 0 or 48, both multiples of 8
    for (int k = 0; k < warm; k += 8) {
        STEP(t0s + k + 0, 0, xstA, false);
        STEP(t0s + k + 1, 1, xstB, false);
        STEP(t0s + k + 2, 2, xstA, false);
        STEP(t0s + k + 3, 3, xstB, false);
        STEP(t0s + k + 4, 4, xstA, false);
        STEP(t0s + k + 5, 5, xstB, false);
        STEP(t0s + k + 6, 6, xstA, false);
        STEP(t0s + k + 7, 7, xstB, false);
    }
    // emit (C multiple of 8)
    for (int k = warm; k < warm + C; k += 8) {
        STEP(t0s + k + 0, 0, xstA, true);
        STEP(t0s + k + 1, 1, xstB, true);
        STEP(t0s + k + 2, 2, xstA, true);
        STEP(t0s + k + 3, 3, xstB, true);
        STEP(t0s + k + 4, 4, xstA, true);
        STEP(t0s + k + 5, 5, xstB, true);
        STEP(t0s + k + 6, 6, xstA, true);
        STEP(t0s + k + 7, 7, xstB, true);
    }
#undef STEP

    if (tend == T_)
        *(float2*)(xlast + (size_t)b * H_ + h0) = xv;
}

// ---------------------------------------------------------------------------
// Kernel 3 v4 (MFMA): out[b,t,o] = sum_h tanh(traj)*W_out[o,h] + b_out[o]
// bf16x3 split (A=Ah+Al, W=Wh+Wl; AhWh+AhWl+AlWh) -> fp32-grade accuracy
// (dropped AlWl ~2^-18 rel). mfma_f32_16x16x32_bf16, verified layouts:
//   A: m=l&15, k=(l>>4)*8+j ; B: n=l&15, k=(l>>4)*8+j ;
//   D: n=l&15, m=(l>>4)*4+reg.
// grid (T/64, B), 256 thr = 4 waves; wave w owns t-rows 16w..16w+15, all 64 o.
// K=512 in 8 chunks of 64. LDS 4 x [64][72] bf16 = 36.9KB -> 4 blocks/CU.
// Stride 72 => uniform 8 lanes/16B-group on b128 frag reads (optimal).
// ---------------------------------------------------------------------------
__global__ __launch_bounds__(256) void out_gemm(
    const float* __restrict__ traj, const float* __restrict__ W_out,
    const float* __restrict__ b_out, float* __restrict__ out)
{
    __shared__ __align__(16) unsigned short sa_hi[64 * 72];
    __shared__ __align__(16) unsigned short sa_lo[64 * 72];
    __shared__ __align__(16) unsigned short sb_hi[64 * 72];
    __shared__ __align__(16) unsigned short sb_lo[64 * 72];

    const int tid = threadIdx.x;
    const int t0  = blockIdx.x * 64;
    const int b   = blockIdx.y;

    const float4* tsrc = (const float4*)(traj + (size_t)(b * T_ + t0) * H_);
    const float4* wsrc = (const float4*)W_out;

    const int lane = tid & 63, wv = tid >> 6;
    const int r  = lane & 15;       // frag row/col within 16
    const int kq = lane >> 4;       // k-quarter

    f32x4 acc[4];
    #pragma unroll
    for (int ot = 0; ot < 4; ++ot) acc[ot] = (f32x4){0.f, 0.f, 0.f, 0.f};

    for (int kc = 0; kc < 8; ++kc) {
        if (kc) __syncthreads();          // prior compute done reading LDS

        // ---- stage chunk kc: 64 rows x 64 k, linear lane-contiguous loads
        #pragma unroll
        for (int j = 0; j < 4; ++j) {
            const int idx = tid + 256 * j;
            const int rw  = idx >> 4;     // 0..63
            const int c4  = idx & 15;     // float4 index within 64-k chunk
            const int ldd = rw * 72 + c4 * 4;

            float4 va = tsrc[(size_t)rw * 128 + kc * 16 + c4];
            va.x = ftanh(va.x); va.y = ftanh(va.y);
            va.z = ftanh(va.z); va.w = ftanh(va.w);
            unsigned int h0 = bfr(va.x), h1 = bfr(va.y),
                         h2 = bfr(va.z), h3 = bfr(va.w);
            unsigned int l0 = bfr(va.x - __uint_as_float(h0 << 16));
            unsigned int l1 = bfr(va.y - __uint_as_float(h1 << 16));
            unsigned int l2 = bfr(va.z - __uint_as_float(h2 << 16));
            unsigned int l3 = bfr(va.w - __uint_as_float(h3 << 16));
            *(uint2*)&sa_hi[ldd] = make_uint2(h0 | (h1 << 16), h2 | (h3 << 16));
            *(uint2*)&sa_lo[ldd] = make_uint2(l0 | (l1 << 16), l2 | (l3 << 16));

            float4 vb = wsrc[(size_t)rw * 128 + kc * 16 + c4];
            unsigned int g0 = bfr(vb.x), g1 = bfr(vb.y),
                         g2 = bfr(vb.z), g3 = bfr(vb.w);
            unsigned int m0 = bfr(vb.x - __uint_as_float(g0 << 16));
            unsigned int m1 = bfr(vb.y - __uint_as_float(g1 << 16));
            unsigned int m2 = bfr(vb.z - __uint_as_float(g2 << 16));
            unsigned int m3 = bfr(vb.w - __uint_as_float(g3 << 16));
            *(uint2*)&sb_hi[ldd] = make_uint2(g0 | (g1 << 16), g2 | (g3 << 16));
            *(uint2*)&sb_lo[ldd] = make_uint2(m0 | (m1 << 16), m2 | (m3 << 16));
        }
        __syncthreads();

        // ---- MFMA: 2 k-steps of 32 within the 64-k chunk
        #pragma unroll
        for (int kk = 0; kk < 2; ++kk) {
            const int k0 = kk * 32 + kq * 8;
            const bf16x8 aH = *(const bf16x8*)&sa_hi[(wv * 16 + r) * 72 + k0];
            const bf16x8 aL = *(const bf16x8*)&sa_lo[(wv * 16 + r) * 72 + k0];
            bf16x8 bH[4], bL[4];
            #pragma unroll
            for (int ot = 0; ot < 4; ++ot) {
                bH[ot] = *(const bf16x8*)&sb_hi[(ot * 16 + r) * 72 + k0];
                bL[ot] = *(const bf16x8*)&sb_lo[(ot * 16 + r) * 72 + k0];
            }
            #pragma unroll
            for (int ot = 0; ot < 4; ++ot)
                acc[ot] = __builtin_amdgcn_mfma_f32_16x16x32_bf16(
                    aH, bH[ot], acc[ot], 0, 0, 0);
            #pragma unroll
            for (int ot = 0; ot < 4; ++ot)
                acc[ot] = __builtin_amdgcn_mfma_f32_16x16x32_bf16(
                    aH, bL[ot], acc[ot], 0, 0, 0);
            #pragma unroll
            for (int ot = 0; ot < 4; ++ot)
                acc[ot] = __builtin_amdgcn_mfma_f32_16x16x32_bf16(
                    aL, bH[ot], acc[ot], 0, 0, 0);
        }
    }

    // ---- epilogue: D: n = r, m = kq*4 + i  (rows t0+wv*16+m)
    #pragma unroll
    for (int ot = 0; ot < 4; ++ot) {
        const float bo = b_out[ot * 16 + r];
        #pragma unroll
        for (int i = 0; i < 4; ++i)
            out[(size_t)(b * T_ + t0 + wv * 16 + kq * 4 + i) * O_ +
                ot * 16 + r] = acc[ot][i] + bo;
    }
}

// ---------------------------------------------------------------------------
extern "C" void kernel_launch(void* const* d_in, const int* in_sizes, int n_in,
                              void* d_out, int out_size, void* d_ws, size_t ws_size,
                              hipStream_t stream)
{
    const float* u     = (const float*)d_in[0];
    const float* x0    = (const float*)d_in[1];
    const float* noise = (const float*)d_in[2];
    const float* L     = (const float*)d_in[3];
    const float* M     = (const float*)d_in[4];
    const float* N     = (const float*)d_in[5];
    const float* W_in  = (const float*)d_in[6];
    const float* b_in  = (const float*)d_in[7];
    const float* W_out = (const float*)d_in[8];
    const float* b_out = (const float*)d_in[9];

    float* out   = (float*)d_out;                       // [B,T,O]
    float* xlast = out + (size_t)B_ * T_ * O_;          // [B,H]
    float* traj  = xlast + (size_t)B_ * H_;             // [B,T,H]

    const size_t drive_bytes = (size_t)B_ * T_ * H_ * sizeof(float);

    if (ws_size >= drive_bytes) {
        // chunk-parallel path: drive lives in the workspace
        float* drive = (float*)d_ws;
        inp_gemm<<<dim3(T_ / 64, H_ / 64, B_), 256, 0, stream>>>(
            u, W_in, b_in, noise, drive);
        scan_chunked<16><<<dim3(16, B_), 256, 0, stream>>>(
            x0, L, M, N, drive, traj, xlast);
    } else {
        // fallback: exact serial in-place scan (drive aliases traj)
        inp_gemm<<<dim3(T_ / 64, H_ / 64, B_), 256, 0, stream>>>(
            u, W_in, b_in, noise, traj);
        scan_chunked<1><<<dim3(1, B_), 256, 0, stream>>>(
            x0, L, M, N, traj, traj, xlast);
    }

    out_gemm<<<dim3(T_ / 64, B_), 256, 0, stream>>>(traj, W_out, b_out, out);
}